// Round 7
// baseline (217.919 us; speedup 1.0000x reference)
//
#include <hip/hip_runtime.h>
#include <cstddef>

#define B_  16384
#define F_  2048
#define T_  64
#define C_  32
#define H_  24
#define HH_ 48
#define THR 256
#define ROWS_BLK 512             // smaller chunk -> 2048 blocks = 8 blocks/CU
#define NCHUNK (B_ / ROWS_BLK)   // 32
#define GRP 8                    // 16-row groups per wave (128 rows/wave)
#define SL_STRIDE 72             // shorts per S_lds row (144 B: 16B-aligned, 2-way banks)

typedef __attribute__((ext_vector_type(8))) short  short8;   // 8 bf16 (4 VGPRs)
typedef __attribute__((ext_vector_type(4))) float  floatx4;

__device__ __forceinline__ short f2bf(float f) {   // fp32 -> bf16 bits, RNE
    union { float f; unsigned u; } v; v.f = f;
    unsigned r = v.u + 0x7FFFu + ((v.u >> 16) & 1u);
    return (short)(r >> 16);
}

// ---------------------------------------------------------------------------
// err_row = s^T (G-2I) s + d.s + k0 + sum_c x_c (x_c - 2 w2_c)
// Both GEMMs via mfma_f32_16x16x32_bf16; W/G'/w2/d in per-wave reg fragments;
// D->A layout hop for the 2nd MFMA via per-wave LDS tile. 2-deep prefetch,
// 8 blocks/CU for latency hiding. x consumed exactly once (one line = one
// (t,chunk) owner).
// ---------------------------------------------------------------------------
__global__ __launch_bounds__(THR) void kitnet_main(
    const float* __restrict__ x, const int* __restrict__ clusters,
    const float* __restrict__ Wt, const float* __restrict__ hb,
    const float* __restrict__ vb, float* __restrict__ partial)
{
    __shared__ __align__(16) float WL[C_ * H_];   // W[c][j]
    __shared__ __align__(16) float GL[H_ * H_];   // G' = W^T W - 2I
    __shared__ __align__(16) float w2L[C_];
    __shared__ __align__(16) float dL[H_];
    __shared__ __align__(16) float hbL[H_];
    __shared__ float k0L;
    __shared__ int   colsL[C_];
    __shared__ int   contigS;
    __shared__ float wsum[4];
    __shared__ __align__(16) short Sl[4 * 16 * SL_STRIDE];  // per-wave S tiles

    const int tid   = threadIdx.x;
    const int t     = blockIdx.x >> 5;            // chunk-fastest: XCD = chunk%8
    const int chunk = blockIdx.x & (NCHUNK - 1);
    const int b0    = chunk * ROWS_BLK;

    // ---- phase 1: stage W, hb, cols ----
    for (int i = tid; i < C_ * H_; i += THR) WL[i] = Wt[t * C_ * H_ + i];
    if (tid < H_) hbL[tid] = hb[t * H_ + tid];
    if (tid < C_) colsL[tid] = clusters[t * C_ + tid];
    __syncthreads();

    // ---- phase 2: w2, contiguity ----
    if (tid < C_) {
        float a = vb[t * C_ + tid];
        #pragma unroll
        for (int j = 0; j < H_; ++j) a += WL[tid * H_ + j] * hbL[j];
        w2L[tid] = a;
    }
    if (tid == 0) {
        int ok = (colsL[0] & 3) == 0;
        for (int c = 1; c < C_; ++c) ok &= (colsL[c] == colsL[0] + c);
        contigS = ok;
    }
    __syncthreads();

    // ---- phase 3: G', d, k0 ----
    for (int idx = tid; idx < H_ * H_; idx += THR) {
        const int i = idx / H_, j = idx - i * H_;
        float a = 0.f;
        #pragma unroll
        for (int c = 0; c < C_; ++c) a += WL[c * H_ + i] * WL[c * H_ + j];
        GL[idx] = (i == j) ? a - 2.f : a;
    }
    if (tid < H_) {
        float a = 0.f;
        #pragma unroll
        for (int c = 0; c < C_; ++c) a += w2L[c] * WL[c * H_ + tid];
        dL[tid] = 2.f * (a - hbL[tid]);
    }
    if (tid == THR - 1) {
        float a = 0.f;
        for (int c = 0; c < C_; ++c) a += w2L[c] * w2L[c];
        k0L = a;
    }
    __syncthreads();

    const int lane = tid & 63;
    const int wid  = tid >> 6;
    const int m    = lane & 15;    // A row / B-D col
    const int quad = lane >> 4;    // k-slice

    // ---- per-wave constant fragments (built once) ----
    short8 bw0, bw1, gg0, gg1;
    float  w2f[8];
    #pragma unroll
    for (int j = 0; j < 8; ++j) {
        const int k = quad * 8 + j;
        bw0[j] = f2bf(WL[k * H_ + m]);                                 // W[c][n]
        bw1[j] = (m < 8) ? f2bf(WL[k * H_ + 16 + m]) : (short)0;       // n=16..23
        gg0[j] = (k < H_) ? f2bf(GL[k * H_ + m]) : (short)0;           // G'[j][i]
        gg1[j] = (k < H_ && m < 8) ? f2bf(GL[k * H_ + 16 + m]) : (short)0;
        w2f[j] = w2L[k];
    }
    const float d0 = dL[m];
    const float d1 = (m < 8) ? dL[16 + m] : 0.f;

    short* sl = &Sl[wid * 16 * SL_STRIDE];
    const int contig = contigS;
    const int col0   = colsL[0];
    float err = 0.f;

#define PROCESS16(X0, X1, X2, X3, X4, X5, X6, X7)                             \
    {                                                                         \
        const float xv_[8] = {X0, X1, X2, X3, X4, X5, X6, X7};                \
        short8 af;                                                            \
        _Pragma("unroll")                                                     \
        for (int j = 0; j < 8; ++j) {                                         \
            err += xv_[j] * (xv_[j] - 2.f * w2f[j]);                          \
            af[j] = f2bf(xv_[j]);                                             \
        }                                                                     \
        const floatx4 z_ = {0.f, 0.f, 0.f, 0.f};                              \
        floatx4 S0 = __builtin_amdgcn_mfma_f32_16x16x32_bf16(af, bw0, z_, 0, 0, 0); \
        floatx4 S1 = __builtin_amdgcn_mfma_f32_16x16x32_bf16(af, bw1, z_, 0, 0, 0); \
        _Pragma("unroll")                                                     \
        for (int r = 0; r < 4; ++r) {                                         \
            sl[(quad * 4 + r) * SL_STRIDE + m]      = f2bf(S0[r]);            \
            sl[(quad * 4 + r) * SL_STRIDE + 16 + m] = f2bf(S1[r]);            \
        }                                                                     \
        short8 sf = *(const short8*)&sl[m * SL_STRIDE + quad * 8];            \
        floatx4 Q0 = __builtin_amdgcn_mfma_f32_16x16x32_bf16(sf, gg0, z_, 0, 0, 0); \
        floatx4 Q1 = __builtin_amdgcn_mfma_f32_16x16x32_bf16(sf, gg1, z_, 0, 0, 0); \
        _Pragma("unroll")                                                     \
        for (int r = 0; r < 4; ++r)                                           \
            err += (Q0[r] + d0) * S0[r] + (Q1[r] + d1) * S1[r];               \
    }

    if (contig) {
        // lane loads 32 B contiguous of its row; 2-deep software pipeline
        const float* xbase = x + (size_t)(b0 + wid * (GRP * 16) + m) * F_ + col0 + quad * 8;
        float4 P0[2], P1[2];
        P0[0] = *(const float4*)xbase;
        P1[0] = *(const float4*)(xbase + 4);
        P0[1] = *(const float4*)(xbase + (size_t)16 * F_);
        P1[1] = *(const float4*)(xbase + (size_t)16 * F_ + 4);
        #pragma unroll
        for (int g = 0; g < GRP; ++g) {
            const float4 xa = P0[g & 1], xb = P1[g & 1];
            if (g + 2 < GRP) {
                const float* nx = xbase + (size_t)(g + 2) * 16 * F_;
                P0[g & 1] = *(const float4*)nx;
                P1[g & 1] = *(const float4*)(nx + 4);
            }
            PROCESS16(xa.x, xa.y, xa.z, xa.w, xb.x, xb.y, xb.z, xb.w)
        }
    } else {
        for (int g = 0; g < GRP; ++g) {
            const size_t rb = (size_t)(b0 + wid * (GRP * 16) + g * 16 + m) * F_;
            float xf[8];
            #pragma unroll
            for (int j = 0; j < 8; ++j) xf[j] = x[rb + colsL[quad * 8 + j]];
            PROCESS16(xf[0], xf[1], xf[2], xf[3], xf[4], xf[5], xf[6], xf[7])
        }
    }
#undef PROCESS16

    // ---- reduce: wave shuffle -> block -> one partial per block ----
    #pragma unroll
    for (int off = 32; off > 0; off >>= 1) err += __shfl_down(err, off, 64);
    if (lane == 0) wsum[wid] = err;
    __syncthreads();
    if (tid == 0)
        partial[blockIdx.x] = wsum[0] + wsum[1] + wsum[2] + wsum[3]
                            + (float)ROWS_BLK * k0L;
}

// ---------------------------------------------------------------------------
// Kernel B: sum partials -> tails -> 2 tiny head matmuls. One wave.
// d_out = [ head_out (64) | tails (64) ]
// ---------------------------------------------------------------------------
__global__ __launch_bounds__(64) void kitnet_head(
    const float* __restrict__ partial, const float* __restrict__ Wh,
    const float* __restrict__ hbh, const float* __restrict__ vbh,
    float* __restrict__ out)
{
    __shared__ float tl[T_];
    __shared__ float hhL[HH_];
    const int tid = threadIdx.x;

    float sse = 0.f;
    #pragma unroll
    for (int c = 0; c < NCHUNK; ++c) sse += partial[tid * NCHUNK + c];  // [t][chunk]

    const float tail = 0.5f * logf(sse * (1.0f / ((float)B_ * (float)C_)));
    tl[tid] = tail;
    out[T_ + tid] = tail;
    __syncthreads();

    if (tid < HH_) {
        float acc = hbh[tid];
        #pragma unroll 8
        for (int t = 0; t < T_; ++t) acc += tl[t] * Wh[t * HH_ + tid];
        hhL[tid] = acc;
    }
    __syncthreads();

    float ho = vbh[tid];
    #pragma unroll 8
    for (int j = 0; j < HH_; ++j) ho += hhL[j] * Wh[tid * HH_ + j];
    out[tid] = ho;
}

extern "C" void kernel_launch(void* const* d_in, const int* in_sizes, int n_in,
                              void* d_out, int out_size, void* d_ws, size_t ws_size,
                              hipStream_t stream)
{
    const float* x        = (const float*)d_in[0];
    const int*   clusters = (const int*)  d_in[1];
    const float* Wt       = (const float*)d_in[2];
    const float* hb       = (const float*)d_in[3];
    const float* vb       = (const float*)d_in[4];
    const float* Wh       = (const float*)d_in[5];
    const float* hbh      = (const float*)d_in[6];
    const float* vbh      = (const float*)d_in[7];
    float* out     = (float*)d_out;
    float* partial = (float*)d_ws;   // T_*NCHUNK floats; every slot written each call

    kitnet_main<<<dim3(T_ * NCHUNK), dim3(THR), 0, stream>>>(x, clusters, Wt, hb, vb, partial);
    kitnet_head<<<dim3(1), dim3(64), 0, stream>>>(partial, Wh, hbh, vbh, out);
}